// Round 12
// baseline (200.234 us; speedup 1.0000x reference)
//
#include <hip/hip_runtime.h>
#include <hip/hip_bf16.h>

// Problem: B=8, N=2048, C=320, H=5, D=64, SCALE=1/8. Inputs f32, output f32.
// out = proj( softmax(Q K^T / 8) V ), qkv = x @ w_qkv^T (w stored [out,in]).
// Kernels: cvt_x (x f32->bf16 once; x is re-read 15x by qkv — pre-convert
// re-read operands, inline-convert read-once operands like w tiles), qkv
// (bf16 A, inline-cvt B), attn, proj (plain bf16, inline-cvt w).
// Attention: Q pre-scaled by 0.125*log2(e) -> softmax = bare exp2. K/V in
// MFMA-fragment order (one coalesced dwordx4 per fragment). 2-wave blocks,
// KV-split halves, end-of-kernel LDS combine. Pointer-increment global
// addressing + immediate-offset LDS (stride-72 pad = free 2-way conflicts).
// TOOLCHAIN RULE (rounds 7 & 9): ANY min-occupancy hint (launch_bounds 2nd
// arg OR amdgpu_waves_per_eu) clamps attn to the 64-VGPR tier and spills
// ~80 live regs (FETCH 87->250+ MB, 2.3-3x slower). Allocator must float.

typedef __attribute__((ext_vector_type(8))) short bf16x8;   // 8 bf16 = 4 VGPRs
typedef __attribute__((ext_vector_type(4))) float f32x4;

#define MFMA(a, b, c) __builtin_amdgcn_mfma_f32_16x16x32_bf16((a), (b), (c), 0, 0, 0)

// Q pre-scale: (1/8) * log2(e)
#define QSCALE 0.18033688322643216f

static __device__ __forceinline__ bf16x8 ld8(const __hip_bfloat16* p) {
    return *reinterpret_cast<const bf16x8*>(p);
}

static __device__ __forceinline__ unsigned short bfbits(float v) {
    __hip_bfloat16 b = __float2bfloat16(v);
    return *reinterpret_cast<unsigned short*>(&b);
}

// convert 8 consecutive f32 to a bf16x8 vector
static __device__ __forceinline__ bf16x8 cvt8(const float* src) {
    float4 a = *reinterpret_cast<const float4*>(src);
    float4 b = *reinterpret_cast<const float4*>(src + 4);
    bf16x8 v;
    v[0] = (short)bfbits(a.x); v[1] = (short)bfbits(a.y);
    v[2] = (short)bfbits(a.z); v[3] = (short)bfbits(a.w);
    v[4] = (short)bfbits(b.x); v[5] = (short)bfbits(b.y);
    v[6] = (short)bfbits(b.z); v[7] = (short)bfbits(b.w);
    return v;
}

// ---------------------------------------------------------------------------
// Kernel 0: x f32 -> bf16 (x is re-read 15x by qkv; convert once).
// ---------------------------------------------------------------------------
__global__ __launch_bounds__(256)
void cvt_x(const float* __restrict__ x, __hip_bfloat16* __restrict__ xb)
{
    const size_t tid = (size_t)blockIdx.x * blockDim.x + threadIdx.x;
    const size_t stride = (size_t)gridDim.x * blockDim.x;
    const float4* x4 = (const float4*)x;
    ushort4* xb4 = (ushort4*)xb;
    for (size_t i = tid; i < 1310720u; i += stride) {   // 5242880/4
        float4 v = x4[i];
        ushort4 u;
        u.x = bfbits(v.x); u.y = bfbits(v.y);
        u.z = bfbits(v.z); u.w = bfbits(v.w);
        xb4[i] = u;
    }
}

// ---------------------------------------------------------------------------
// Kernel 1: QKV GEMM, plain bf16, BK=64. A = xb (bf16), B = w_qkv (f32,
// converted inline while staging — w tiles are read-once per block).
// out[m][n] = sum_k x[m][k]*w[n][k], M=16384, N=960, K=320.
// Q written row-major [bh][n][d] PRE-SCALED by QSCALE.
// K in B-fragment order K', V in B-fragment order V'.
// ---------------------------------------------------------------------------
__global__ __launch_bounds__(256)
void qkv_kernel(const __hip_bfloat16* __restrict__ xb,
                const float* __restrict__ w,
                __hip_bfloat16* __restrict__ qout,
                __hip_bfloat16* __restrict__ kp,
                __hip_bfloat16* __restrict__ vp)
{
    __shared__ __align__(16) __hip_bfloat16 As[128 * 72];  // 128x64, pad->72
    __shared__ __align__(16) __hip_bfloat16 Bs[64 * 72];   // 64x64,  pad->72

    const int tid  = threadIdx.x;
    const int wv   = tid >> 6;
    const int lane = tid & 63;
    const int quad = lane >> 4;
    const int col  = lane & 15;
    const int m0   = blockIdx.x * 128;
    const int n0   = blockIdx.y * 64;

    f32x4 acc[2][4];
#pragma unroll
    for (int i = 0; i < 2; ++i)
#pragma unroll
        for (int j = 0; j < 4; ++j) acc[i][j] = (f32x4){0.f, 0.f, 0.f, 0.f};

    for (int k0 = 0; k0 < 320; k0 += 64) {
        __syncthreads();
        // stage A 128x64 bf16 (1024 16B-chunks, 4/thread) — plain copies
#pragma unroll
        for (int i = 0; i < 4; ++i) {
            int ch = tid + i * 256;
            int r = ch >> 3, sg = ch & 7;
            *reinterpret_cast<float4*>(&As[r * 72 + sg * 8]) =
                *reinterpret_cast<const float4*>(&xb[(m0 + r) * 320 + k0 + sg * 8]);
        }
        // stage B 64x64 (f32 -> bf16 inline; 2 chunks/thread)
#pragma unroll
        for (int i = 0; i < 2; ++i) {
            int ch = tid + i * 256;
            int r = ch >> 3, sg = ch & 7;
            *reinterpret_cast<bf16x8*>(&Bs[r * 72 + sg * 8]) =
                cvt8(&w[(n0 + r) * 320 + k0 + sg * 8]);
        }
        __syncthreads();

#pragma unroll
        for (int hf = 0; hf < 2; ++hf) {
            bf16x8 a0 = ld8(&As[(wv * 32 + col) * 72 + hf * 32 + quad * 8]);
            bf16x8 a1 = ld8(&As[(wv * 32 + 16 + col) * 72 + hf * 32 + quad * 8]);
#pragma unroll
            for (int nt = 0; nt < 4; ++nt) {
                bf16x8 b = ld8(&Bs[(nt * 16 + col) * 72 + hf * 32 + quad * 8]);
                acc[0][nt] = MFMA(a0, b, acc[0][nt]);
                acc[1][nt] = MFMA(a1, b, acc[1][nt]);
            }
        }
    }

    const int s = blockIdx.y / 5;   // 0=Q,1=K,2=V
    const int h = blockIdx.y % 5;
#pragma unroll
    for (int mt = 0; mt < 2; ++mt) {
#pragma unroll
        for (int nt = 0; nt < 4; ++nt) {
#pragma unroll
            for (int r = 0; r < 4; ++r) {
                int m = m0 + wv * 32 + mt * 16 + quad * 4 + r;
                int d = nt * 16 + col;
                int b = m >> 11, n = m & 2047;
                int bh = b * 5 + h;
                float val = acc[mt][nt][r];
                if (s == 0) {
                    qout[((size_t)bh * 2048 + n) * 64 + d] =
                        __float2bfloat16(val * QSCALE);
                } else if (s == 1) {
                    int p = n >> 6, nn = n & 63;
                    size_t a = ((size_t)(bh * 32 + p) * 8 + (d >> 5) * 4 + (nn >> 4)) * 512
                             + (((d >> 3) & 3) * 16 + (nn & 15)) * 8 + (d & 7);
                    kp[a] = __float2bfloat16(val);
                } else {
                    int p = n >> 6;
                    size_t a = ((size_t)(bh * 32 + p) * 8 + ((n >> 5) & 1) * 4 + (d >> 4)) * 512
                             + (((n >> 3) & 3) * 16 + (d & 15)) * 8 + (n & 7);
                    vp[a] = __float2bfloat16(val);
                }
            }
        }
    }
}

// ---------------------------------------------------------------------------
// Kernel 2: flash attention, fragment-order K'/V', KV-split 2-wave blocks.
// Unchanged from round 11 (80.9 µs, VGPR 116 floating).
// ---------------------------------------------------------------------------
__global__ __launch_bounds__(128)
void attn_kernel(const __hip_bfloat16* __restrict__ Q,
                 const __hip_bfloat16* __restrict__ Kp,
                 const __hip_bfloat16* __restrict__ Vp,
                 __hip_bfloat16* __restrict__ A2)
{
    // union: per-wave Ps (2 x 32x72 bf16 = 9216 B) / end-of-kernel combine
    __shared__ __align__(16) unsigned char smraw[9216];

    const int tid  = threadIdx.x;
    const int wv   = tid >> 6;
    const int lane = tid & 63;
    const int quad = lane >> 4;
    const int col  = lane & 15;
    const int bh = blockIdx.y, b = bh / 5, h = bh % 5;
    const int q0 = blockIdx.x * 32;
    const int t0 = wv * 16;

    __hip_bfloat16* Ps = (__hip_bfloat16*)smraw + wv * 2304;       // 32*72
    __hip_bfloat16* ps_w = Ps + (quad * 4) * 72 + col;             // + (mt*16+r)*72 + nt*16
    const __hip_bfloat16* ps_r = Ps + col * 72 + quad * 8;         // + mt*1152 + kk*32

    const __hip_bfloat16* kt = Kp + (size_t)bh * 131072 + (size_t)t0 * 4096 + lane * 8;
    const __hip_bfloat16* vt = Vp + (size_t)bh * 131072 + (size_t)t0 * 4096 + lane * 8;
    const __hip_bfloat16* Qh = Q + (size_t)bh * 131072;

    // Q fragments (A-layout): rows q0+mt*16+col, k = hf*32+quad*8+j
    bf16x8 qf[2][2];
#pragma unroll
    for (int mt = 0; mt < 2; ++mt)
#pragma unroll
        for (int hf = 0; hf < 2; ++hf)
            qf[mt][hf] = ld8(&Qh[(q0 + mt * 16 + col) * 64 + hf * 32 + quad * 8]);

    f32x4 lp[2];
    f32x4 o[2][4];
#pragma unroll
    for (int mt = 0; mt < 2; ++mt) {
        lp[mt] = (f32x4){0.f, 0.f, 0.f, 0.f};
#pragma unroll
        for (int dt = 0; dt < 4; ++dt) o[mt][dt] = (f32x4){0.f, 0.f, 0.f, 0.f};
    }

    // preload first K panel
    bf16x8 ka[8];
#pragma unroll
    for (int f = 0; f < 8; ++f) ka[f] = ld8(kt + f * 512);
    kt += 4096;

    for (int t = 0; t < 16; ++t) {
        // QK^T: ka[f] = frag(hf=f>>2, nt=f&3)
        f32x4 s[2][4];
#pragma unroll
        for (int mt = 0; mt < 2; ++mt)
#pragma unroll
            for (int nt = 0; nt < 4; ++nt) {
                f32x4 z = (f32x4){0.f, 0.f, 0.f, 0.f};
                z = MFMA(qf[mt][0], ka[nt], z);
                z = MFMA(qf[mt][1], ka[4 + nt], z);
                s[mt][nt] = z;
            }

        // V loads for THIS tile (in flight across exp; PV waits on them)
        bf16x8 va[8];
#pragma unroll
        for (int f = 0; f < 8; ++f) va[f] = ld8(vt + f * 512);
        vt += 4096;

        // unconditional prefetch of next K panel (one-past read lands in the
        // adjacent allocated vp buffer on the final panel)
#pragma unroll
        for (int f = 0; f < 8; ++f) ka[f] = ld8(kt + f * 512);
        kt += 4096;

        // softmax: p = exp2(z); C-layout -> Ps via imm-offset stores
#pragma unroll
        for (int mt = 0; mt < 2; ++mt)
#pragma unroll
            for (int nt = 0; nt < 4; ++nt) {
                f32x4 pv;
#pragma unroll
                for (int r = 0; r < 4; ++r)
                    pv[r] = __builtin_amdgcn_exp2f(s[mt][nt][r]);
                lp[mt] += pv;
#pragma unroll
                for (int r = 0; r < 4; ++r)
                    ps_w[(mt * 16 + r) * 72 + nt * 16] = __float2bfloat16(pv[r]);
            }
        __asm__ volatile("s_waitcnt lgkmcnt(0)" ::: "memory");

        // PV: A-layout P reads (imm offsets); va[f] = frag(kk=f>>2, dt=f&3)
#pragma unroll
        for (int mt = 0; mt < 2; ++mt)
#pragma unroll
            for (int kk = 0; kk < 2; ++kk) {
                bf16x8 pf = ld8(ps_r + mt * 1152 + kk * 32);
#pragma unroll
                for (int dt = 0; dt < 4; ++dt)
                    o[mt][dt] = MFMA(pf, va[kk * 4 + dt], o[mt][dt]);
            }
    }

    // per-wave row-sum over the 16-lane col group
    float lval[2][4];
#pragma unroll
    for (int mt = 0; mt < 2; ++mt)
#pragma unroll
        for (int r = 0; r < 4; ++r) {
            float v = lp[mt][r];
#pragma unroll
            for (int off = 1; off < 16; off <<= 1)
                v += __shfl_xor(v, off, 64);
            lval[mt][r] = v;
        }

    // combine the two KV-half partials through LDS
    float* cbo = (float*)smraw;        // [32][64]
    float* cbl = cbo + 2048;           // [32]
    __syncthreads();                   // both waves done with Ps
    if (wv == 1) {
#pragma unroll
        for (int mt = 0; mt < 2; ++mt)
#pragma unroll
            for (int dt = 0; dt < 4; ++dt)
#pragma unroll
                for (int r = 0; r < 4; ++r)
                    cbo[(mt * 16 + quad * 4 + r) * 64 + dt * 16 + col] = o[mt][dt][r];
        if (col == 0)
#pragma unroll
            for (int mt = 0; mt < 2; ++mt)
#pragma unroll
                for (int r = 0; r < 4; ++r)
                    cbl[mt * 16 + quad * 4 + r] = lval[mt][r];
    }
    __syncthreads();
    if (wv == 0) {
#pragma unroll
        for (int mt = 0; mt < 2; ++mt) {
#pragma unroll
            for (int r = 0; r < 4; ++r) {
                int row = mt * 16 + quad * 4 + r;
                float inv = 1.0f / (lval[mt][r] + cbl[row]);
                int grow = q0 + row;
#pragma unroll
                for (int dt = 0; dt < 4; ++dt) {
                    int d = dt * 16 + col;
                    float val = (o[mt][dt][r] + cbo[row * 64 + d]) * inv;
                    A2[((size_t)(b * 2048 + grow)) * 320 + h * 64 + d] =
                        __float2bfloat16(val);
                }
            }
        }
    }
}

// ---------------------------------------------------------------------------
// Kernel 3: output projection, plain bf16, BK=64, inline w conversion.
// out[m][n] = sum_k a2[m][k]*w[n][k] + bias[n], M=16384, N=320, K=320.
// Plain-bf16 error verified: absmax 0.0024 vs threshold 0.0101 (round 11).
// ---------------------------------------------------------------------------
__global__ __launch_bounds__(256)
void proj_kernel(const __hip_bfloat16* __restrict__ a2,
                 const float* __restrict__ w,
                 const float* __restrict__ bias,
                 float* __restrict__ out)
{
    __shared__ __align__(16) __hip_bfloat16 As[128 * 72];  // 128x64, pad->72
    __shared__ __align__(16) __hip_bfloat16 Bs[64 * 72];   // 64x64,  pad->72

    const int tid  = threadIdx.x;
    const int wv   = tid >> 6;
    const int lane = tid & 63;
    const int quad = lane >> 4;
    const int col  = lane & 15;
    const int m0   = blockIdx.x * 128;
    const int n0   = blockIdx.y * 64;

    f32x4 acc[2][4];
#pragma unroll
    for (int i = 0; i < 2; ++i)
#pragma unroll
        for (int j = 0; j < 4; ++j) acc[i][j] = (f32x4){0.f, 0.f, 0.f, 0.f};

    for (int k0 = 0; k0 < 320; k0 += 64) {
        __syncthreads();
        // stage A (a2, already bf16): 4 x 16B copies per thread
#pragma unroll
        for (int i = 0; i < 4; ++i) {
            int ch = tid + i * 256;
            int r = ch >> 3, sg = ch & 7;
            *reinterpret_cast<float4*>(&As[r * 72 + sg * 8]) =
                *reinterpret_cast<const float4*>(&a2[(m0 + r) * 320 + k0 + sg * 8]);
        }
        // stage B (w_proj f32 -> bf16 inline)
#pragma unroll
        for (int i = 0; i < 2; ++i) {
            int ch = tid + i * 256;
            int r = ch >> 3, sg = ch & 7;
            *reinterpret_cast<bf16x8*>(&Bs[r * 72 + sg * 8]) =
                cvt8(&w[(n0 + r) * 320 + k0 + sg * 8]);
        }
        __syncthreads();

#pragma unroll
        for (int hf = 0; hf < 2; ++hf) {
            bf16x8 a0 = ld8(&As[(wv * 32 + col) * 72 + hf * 32 + quad * 8]);
            bf16x8 a1 = ld8(&As[(wv * 32 + 16 + col) * 72 + hf * 32 + quad * 8]);
#pragma unroll
            for (int nt = 0; nt < 4; ++nt) {
                bf16x8 b = ld8(&Bs[(nt * 16 + col) * 72 + hf * 32 + quad * 8]);
                acc[0][nt] = MFMA(a0, b, acc[0][nt]);
                acc[1][nt] = MFMA(a1, b, acc[1][nt]);
            }
        }
    }

#pragma unroll
    for (int nt = 0; nt < 4; ++nt) {
        float bv = bias[n0 + nt * 16 + col];
#pragma unroll
        for (int mt = 0; mt < 2; ++mt) {
#pragma unroll
            for (int r = 0; r < 4; ++r) {
                int m = m0 + wv * 32 + mt * 16 + quad * 4 + r;
                out[(size_t)m * 320 + n0 + nt * 16 + col] = acc[mt][nt][r] + bv;
            }
        }
    }
}

// ---------------------------------------------------------------------------
extern "C" void kernel_launch(void* const* d_in, const int* in_sizes, int n_in,
                              void* d_out, int out_size, void* d_ws, size_t ws_size,
                              hipStream_t stream)
{
    const float* x      = (const float*)d_in[0];  // [8,2048,320]
    const float* w_qkv  = (const float*)d_in[1];  // [960,320]
    const float* w_proj = (const float*)d_in[2];  // [320,320]
    const float* b_proj = (const float*)d_in[3];  // [320]
    float* out = (float*)d_out;                   // [8,2048,320] f32

    const size_t NX = 5242880;
    __hip_bfloat16* xb = (__hip_bfloat16*)d_ws;   // [B,N,C] bf16 (reused as a2)
    __hip_bfloat16* q  = xb + NX;                 // [bh][n][d], pre-scaled
    __hip_bfloat16* kp = q + NX;                  // K' fragment order
    __hip_bfloat16* vp = kp + NX;                 // V' fragment order (adjacent:
                                                  //  one-past K prefetch lands here)
    __hip_bfloat16* a2 = xb;                      // alias: xb dead after qkv

    cvt_x<<<1024, 256, 0, stream>>>(x, xb);
    qkv_kernel<<<dim3(128, 15), 256, 0, stream>>>(xb, w_qkv, q, kp, vp);
    attn_kernel<<<dim3(64, 40), 128, 0, stream>>>(q, kp, vp, a2);
    proj_kernel<<<dim3(128, 5), 256, 0, stream>>>(a2, w_proj, b_proj, out);
}

// Round 14
// 187.536 us; speedup vs baseline: 1.0677x; 1.0677x over previous
//
#include <hip/hip_runtime.h>
#include <hip/hip_bf16.h>

// Problem: B=8, N=2048, C=320, H=5, D=64, SCALE=1/8. Inputs f32, output f32.
// out = proj( softmax(Q K^T / 8) V ), qkv = x @ w_qkv^T (w stored [out,in]).
// Kernels: cvt_x, qkv (bf16 A, inline-cvt B), attn, proj (plain bf16).
// Attention: Q pre-scaled by 0.125*log2(e) -> softmax = bare exp2. K/V in
// MFMA-fragment order (one coalesced dwordx4 per fragment). 2-wave blocks,
// KV-split halves, end-of-kernel LDS combine. Pointer-increment global
// addressing + immediate-offset LDS (stride-72 pad = free 2-way conflicts).
// ROUND 14: fast 3-inst bf16 pack (exact RNE for finite values; pipeline is
// NaN-free) replaces __float2bfloat16 (~6-10 insts w/ NaN handling) — it was
// a large share of attn VALU (est. ~970 VALU-cyc/wave-tile vs ~130 intrinsic).
// TOOLCHAIN RULE (rounds 7 & 9): ANY min-occupancy hint (launch_bounds 2nd
// arg OR amdgpu_waves_per_eu) clamps attn to the 64-VGPR tier and spills
// ~80 live regs (FETCH 87->250+ MB, 2.3-3x slower). Allocator must float.

typedef __attribute__((ext_vector_type(8))) short bf16x8;   // 8 bf16 = 4 VGPRs
typedef __attribute__((ext_vector_type(4))) float f32x4;

#define MFMA(a, b, c) __builtin_amdgcn_mfma_f32_16x16x32_bf16((a), (b), (c), 0, 0, 0)

// Q pre-scale: (1/8) * log2(e)
#define QSCALE 0.18033688322643216f

static __device__ inline bf16x8 ld8(const __hip_bfloat16* p) {
    return *reinterpret_cast<const bf16x8*>(p);
}

// fast f32->bf16: exact round-to-nearest-even for all FINITE values (no
// NaN/Inf handling — this pipeline is NaN-free). 3 VALU insts vs ~6-10 for
// __float2bfloat16.
static __device__ inline unsigned short bfbits(float v) {
    unsigned int u = __builtin_bit_cast(unsigned int, v);
    u += 0x7FFFu + ((u >> 16) & 1u);
    return (unsigned short)(u >> 16);
}

// convert 8 consecutive f32 to a bf16x8 vector (fast pack)
static __device__ inline bf16x8 cvt8(const float* src) {
    float4 a = *reinterpret_cast<const float4*>(src);
    float4 b = *reinterpret_cast<const float4*>(src + 4);
    bf16x8 v;
    v[0] = (short)bfbits(a.x); v[1] = (short)bfbits(a.y);
    v[2] = (short)bfbits(a.z); v[3] = (short)bfbits(a.w);
    v[4] = (short)bfbits(b.x); v[5] = (short)bfbits(b.y);
    v[6] = (short)bfbits(b.z); v[7] = (short)bfbits(b.w);
    return v;
}

// ---------------------------------------------------------------------------
// Kernel 0: x f32 -> bf16 (x is re-read 15x by qkv; convert once).
// ---------------------------------------------------------------------------
__global__ __launch_bounds__(256)
void cvt_x(const float* __restrict__ x, __hip_bfloat16* __restrict__ xb)
{
    const size_t tid = (size_t)blockIdx.x * blockDim.x + threadIdx.x;
    const size_t stride = (size_t)gridDim.x * blockDim.x;
    const float4* x4 = (const float4*)x;
    ushort4* xb4 = (ushort4*)xb;
    for (size_t i = tid; i < 1310720u; i += stride) {   // 5242880/4
        float4 v = x4[i];
        ushort4 u;
        u.x = bfbits(v.x); u.y = bfbits(v.y);
        u.z = bfbits(v.z); u.w = bfbits(v.w);
        xb4[i] = u;
    }
}

// ---------------------------------------------------------------------------
// Kernel 1: QKV GEMM, plain bf16, BK=64. A = xb (bf16), B = w_qkv (f32,
// converted inline — read-once per block). M=16384, N=960, K=320.
// Q written row-major [bh][n][d] PRE-SCALED by QSCALE.
// K in B-fragment order K', V in B-fragment order V'.
// ---------------------------------------------------------------------------
__global__ __launch_bounds__(256)
void qkv_kernel(const __hip_bfloat16* __restrict__ xb,
                const float* __restrict__ w,
                __hip_bfloat16* __restrict__ qout,
                __hip_bfloat16* __restrict__ kp,
                __hip_bfloat16* __restrict__ vp)
{
    __shared__ __align__(16) __hip_bfloat16 As[128 * 72];  // 128x64, pad->72
    __shared__ __align__(16) __hip_bfloat16 Bs[64 * 72];   // 64x64,  pad->72

    const int tid  = threadIdx.x;
    const int wv   = tid >> 6;
    const int lane = tid & 63;
    const int quad = lane >> 4;
    const int col  = lane & 15;
    const int m0   = blockIdx.x * 128;
    const int n0   = blockIdx.y * 64;

    f32x4 acc[2][4];
#pragma unroll
    for (int i = 0; i < 2; ++i)
#pragma unroll
        for (int j = 0; j < 4; ++j) acc[i][j] = (f32x4){0.f, 0.f, 0.f, 0.f};

    for (int k0 = 0; k0 < 320; k0 += 64) {
        __syncthreads();
#pragma unroll
        for (int i = 0; i < 4; ++i) {
            int ch = tid + i * 256;
            int r = ch >> 3, sg = ch & 7;
            *reinterpret_cast<float4*>(&As[r * 72 + sg * 8]) =
                *reinterpret_cast<const float4*>(&xb[(m0 + r) * 320 + k0 + sg * 8]);
        }
#pragma unroll
        for (int i = 0; i < 2; ++i) {
            int ch = tid + i * 256;
            int r = ch >> 3, sg = ch & 7;
            *reinterpret_cast<bf16x8*>(&Bs[r * 72 + sg * 8]) =
                cvt8(&w[(n0 + r) * 320 + k0 + sg * 8]);
        }
        __syncthreads();

#pragma unroll
        for (int hf = 0; hf < 2; ++hf) {
            bf16x8 a0 = ld8(&As[(wv * 32 + col) * 72 + hf * 32 + quad * 8]);
            bf16x8 a1 = ld8(&As[(wv * 32 + 16 + col) * 72 + hf * 32 + quad * 8]);
#pragma unroll
            for (int nt = 0; nt < 4; ++nt) {
                bf16x8 b = ld8(&Bs[(nt * 16 + col) * 72 + hf * 32 + quad * 8]);
                acc[0][nt] = MFMA(a0, b, acc[0][nt]);
                acc[1][nt] = MFMA(a1, b, acc[1][nt]);
            }
        }
    }

    const int s = blockIdx.y / 5;   // 0=Q,1=K,2=V
    const int h = blockIdx.y % 5;
    unsigned short* qo = (unsigned short*)qout;
    unsigned short* ko = (unsigned short*)kp;
    unsigned short* vo = (unsigned short*)vp;
#pragma unroll
    for (int mt = 0; mt < 2; ++mt) {
#pragma unroll
        for (int nt = 0; nt < 4; ++nt) {
#pragma unroll
            for (int r = 0; r < 4; ++r) {
                int m = m0 + wv * 32 + mt * 16 + quad * 4 + r;
                int d = nt * 16 + col;
                int b = m >> 11, n = m & 2047;
                int bh = b * 5 + h;
                float val = acc[mt][nt][r];
                if (s == 0) {
                    qo[((size_t)bh * 2048 + n) * 64 + d] = bfbits(val * QSCALE);
                } else if (s == 1) {
                    int p = n >> 6, nn = n & 63;
                    size_t a = ((size_t)(bh * 32 + p) * 8 + (d >> 5) * 4 + (nn >> 4)) * 512
                             + (((d >> 3) & 3) * 16 + (nn & 15)) * 8 + (d & 7);
                    ko[a] = bfbits(val);
                } else {
                    int p = n >> 6;
                    size_t a = ((size_t)(bh * 32 + p) * 8 + ((n >> 5) & 1) * 4 + (d >> 4)) * 512
                             + (((n >> 3) & 3) * 16 + (d & 15)) * 8 + (n & 7);
                    vo[a] = bfbits(val);
                }
            }
        }
    }
}

// ---------------------------------------------------------------------------
// Kernel 2: flash attention, fragment-order K'/V', KV-split 2-wave blocks.
// Fast bf16 pack in the softmax->Ps path (was a large share of VALU).
// ---------------------------------------------------------------------------
__global__ __launch_bounds__(128)
void attn_kernel(const __hip_bfloat16* __restrict__ Q,
                 const __hip_bfloat16* __restrict__ Kp,
                 const __hip_bfloat16* __restrict__ Vp,
                 __hip_bfloat16* __restrict__ A2)
{
    // union: per-wave Ps (2 x 32x72 bf16 = 9216 B) / end-of-kernel combine
    __shared__ __align__(16) unsigned char smraw[9216];

    const int tid  = threadIdx.x;
    const int wv   = tid >> 6;
    const int lane = tid & 63;
    const int quad = lane >> 4;
    const int col  = lane & 15;
    const int bh = blockIdx.y, b = bh / 5, h = bh % 5;
    const int q0 = blockIdx.x * 32;
    const int t0 = wv * 16;

    __hip_bfloat16* Ps = (__hip_bfloat16*)smraw + wv * 2304;       // 32*72
    unsigned short* ps_w = (unsigned short*)(Ps + (quad * 4) * 72 + col);
    const __hip_bfloat16* ps_r = Ps + col * 72 + quad * 8;         // + mt*1152 + kk*32

    const __hip_bfloat16* kt = Kp + (size_t)bh * 131072 + (size_t)t0 * 4096 + lane * 8;
    const __hip_bfloat16* vt = Vp + (size_t)bh * 131072 + (size_t)t0 * 4096 + lane * 8;
    const __hip_bfloat16* Qh = Q + (size_t)bh * 131072;

    // Q fragments (A-layout): rows q0+mt*16+col, k = hf*32+quad*8+j
    bf16x8 qf[2][2];
#pragma unroll
    for (int mt = 0; mt < 2; ++mt)
#pragma unroll
        for (int hf = 0; hf < 2; ++hf)
            qf[mt][hf] = ld8(&Qh[(q0 + mt * 16 + col) * 64 + hf * 32 + quad * 8]);

    f32x4 lp[2];
    f32x4 o[2][4];
#pragma unroll
    for (int mt = 0; mt < 2; ++mt) {
        lp[mt] = (f32x4){0.f, 0.f, 0.f, 0.f};
#pragma unroll
        for (int dt = 0; dt < 4; ++dt) o[mt][dt] = (f32x4){0.f, 0.f, 0.f, 0.f};
    }

    // preload first K panel
    bf16x8 ka[8];
#pragma unroll
    for (int f = 0; f < 8; ++f) ka[f] = ld8(kt + f * 512);
    kt += 4096;

    for (int t = 0; t < 16; ++t) {
        // QK^T: ka[f] = frag(hf=f>>2, nt=f&3)
        f32x4 s[2][4];
#pragma unroll
        for (int mt = 0; mt < 2; ++mt)
#pragma unroll
            for (int nt = 0; nt < 4; ++nt) {
                f32x4 z = (f32x4){0.f, 0.f, 0.f, 0.f};
                z = MFMA(qf[mt][0], ka[nt], z);
                z = MFMA(qf[mt][1], ka[4 + nt], z);
                s[mt][nt] = z;
            }

        // V loads for THIS tile (in flight across exp; PV waits on them)
        bf16x8 va[8];
#pragma unroll
        for (int f = 0; f < 8; ++f) va[f] = ld8(vt + f * 512);
        vt += 4096;

        // unconditional prefetch of next K panel (one-past read lands in the
        // adjacent allocated vp buffer on the final panel)
#pragma unroll
        for (int f = 0; f < 8; ++f) ka[f] = ld8(kt + f * 512);
        kt += 4096;

        // softmax: p = exp2(z); C-layout -> Ps via imm-offset stores,
        // fast 3-inst bf16 pack
#pragma unroll
        for (int mt = 0; mt < 2; ++mt)
#pragma unroll
            for (int nt = 0; nt < 4; ++nt) {
                f32x4 pv;
#pragma unroll
                for (int r = 0; r < 4; ++r)
                    pv[r] = __builtin_amdgcn_exp2f(s[mt][nt][r]);
                lp[mt] += pv;
#pragma unroll
                for (int r = 0; r < 4; ++r)
                    ps_w[(mt * 16 + r) * 72 + nt * 16] = bfbits(pv[r]);
            }
        __asm__ volatile("s_waitcnt lgkmcnt(0)" ::: "memory");

        // PV: A-layout P reads (imm offsets); va[f] = frag(kk=f>>2, dt=f&3)
#pragma unroll
        for (int mt = 0; mt < 2; ++mt)
#pragma unroll
            for (int kk = 0; kk < 2; ++kk) {
                bf16x8 pf = ld8(ps_r + mt * 1152 + kk * 32);
#pragma unroll
                for (int dt = 0; dt < 4; ++dt)
                    o[mt][dt] = MFMA(pf, va[kk * 4 + dt], o[mt][dt]);
            }
    }

    // per-wave row-sum over the 16-lane col group
    float lval[2][4];
#pragma unroll
    for (int mt = 0; mt < 2; ++mt)
#pragma unroll
        for (int r = 0; r < 4; ++r) {
            float v = lp[mt][r];
#pragma unroll
            for (int off = 1; off < 16; off <<= 1)
                v += __shfl_xor(v, off, 64);
            lval[mt][r] = v;
        }

    // combine the two KV-half partials through LDS
    float* cbo = (float*)smraw;        // [32][64]
    float* cbl = cbo + 2048;           // [32]
    __syncthreads();                   // both waves done with Ps
    if (wv == 1) {
#pragma unroll
        for (int mt = 0; mt < 2; ++mt)
#pragma unroll
            for (int dt = 0; dt < 4; ++dt)
#pragma unroll
                for (int r = 0; r < 4; ++r)
                    cbo[(mt * 16 + quad * 4 + r) * 64 + dt * 16 + col] = o[mt][dt][r];
        if (col == 0)
#pragma unroll
            for (int mt = 0; mt < 2; ++mt)
#pragma unroll
                for (int r = 0; r < 4; ++r)
                    cbl[mt * 16 + quad * 4 + r] = lval[mt][r];
    }
    __syncthreads();
    if (wv == 0) {
        unsigned short* a2o = (unsigned short*)A2;
#pragma unroll
        for (int mt = 0; mt < 2; ++mt) {
#pragma unroll
            for (int r = 0; r < 4; ++r) {
                int row = mt * 16 + quad * 4 + r;
                float inv = 1.0f / (lval[mt][r] + cbl[row]);
                int grow = q0 + row;
#pragma unroll
                for (int dt = 0; dt < 4; ++dt) {
                    int d = dt * 16 + col;
                    float val = (o[mt][dt][r] + cbo[row * 64 + d]) * inv;
                    a2o[((size_t)(b * 2048 + grow)) * 320 + h * 64 + d] = bfbits(val);
                }
            }
        }
    }
}

// ---------------------------------------------------------------------------
// Kernel 3: output projection, plain bf16, BK=64, inline w conversion.
// out[m][n] = sum_k a2[m][k]*w[n][k] + bias[n], M=16384, N=320, K=320.
// Plain-bf16 error verified: absmax 0.0024 vs threshold 0.0101 (round 11).
// ---------------------------------------------------------------------------
__global__ __launch_bounds__(256)
void proj_kernel(const __hip_bfloat16* __restrict__ a2,
                 const float* __restrict__ w,
                 const float* __restrict__ bias,
                 float* __restrict__ out)
{
    __shared__ __align__(16) __hip_bfloat16 As[128 * 72];  // 128x64, pad->72
    __shared__ __align__(16) __hip_bfloat16 Bs[64 * 72];   // 64x64,  pad->72

    const int tid  = threadIdx.x;
    const int wv   = tid >> 6;
    const int lane = tid & 63;
    const int quad = lane >> 4;
    const int col  = lane & 15;
    const int m0   = blockIdx.x * 128;
    const int n0   = blockIdx.y * 64;

    f32x4 acc[2][4];
#pragma unroll
    for (int i = 0; i < 2; ++i)
#pragma unroll
        for (int j = 0; j < 4; ++j) acc[i][j] = (f32x4){0.f, 0.f, 0.f, 0.f};

    for (int k0 = 0; k0 < 320; k0 += 64) {
        __syncthreads();
#pragma unroll
        for (int i = 0; i < 4; ++i) {
            int ch = tid + i * 256;
            int r = ch >> 3, sg = ch & 7;
            *reinterpret_cast<float4*>(&As[r * 72 + sg * 8]) =
                *reinterpret_cast<const float4*>(&a2[(m0 + r) * 320 + k0 + sg * 8]);
        }
#pragma unroll
        for (int i = 0; i < 2; ++i) {
            int ch = tid + i * 256;
            int r = ch >> 3, sg = ch & 7;
            *reinterpret_cast<bf16x8*>(&Bs[r * 72 + sg * 8]) =
                cvt8(&w[(n0 + r) * 320 + k0 + sg * 8]);
        }
        __syncthreads();

#pragma unroll
        for (int hf = 0; hf < 2; ++hf) {
            bf16x8 a0 = ld8(&As[(wv * 32 + col) * 72 + hf * 32 + quad * 8]);
            bf16x8 a1 = ld8(&As[(wv * 32 + 16 + col) * 72 + hf * 32 + quad * 8]);
#pragma unroll
            for (int nt = 0; nt < 4; ++nt) {
                bf16x8 b = ld8(&Bs[(nt * 16 + col) * 72 + hf * 32 + quad * 8]);
                acc[0][nt] = MFMA(a0, b, acc[0][nt]);
                acc[1][nt] = MFMA(a1, b, acc[1][nt]);
            }
        }
    }

#pragma unroll
    for (int nt = 0; nt < 4; ++nt) {
        float bv = bias[n0 + nt * 16 + col];
#pragma unroll
        for (int mt = 0; mt < 2; ++mt) {
#pragma unroll
            for (int r = 0; r < 4; ++r) {
                int m = m0 + wv * 32 + mt * 16 + quad * 4 + r;
                out[(size_t)m * 320 + n0 + nt * 16 + col] = acc[mt][nt][r] + bv;
            }
        }
    }
}

// ---------------------------------------------------------------------------
extern "C" void kernel_launch(void* const* d_in, const int* in_sizes, int n_in,
                              void* d_out, int out_size, void* d_ws, size_t ws_size,
                              hipStream_t stream)
{
    const float* x      = (const float*)d_in[0];  // [8,2048,320]
    const float* w_qkv  = (const float*)d_in[1];  // [960,320]
    const float* w_proj = (const float*)d_in[2];  // [320,320]
    const float* b_proj = (const float*)d_in[3];  // [320]
    float* out = (float*)d_out;                   // [8,2048,320] f32

    const size_t NX = 5242880;
    __hip_bfloat16* xb = (__hip_bfloat16*)d_ws;   // [B,N,C] bf16 (reused as a2)
    __hip_bfloat16* q  = xb + NX;                 // [bh][n][d], pre-scaled
    __hip_bfloat16* kp = q + NX;                  // K' fragment order
    __hip_bfloat16* vp = kp + NX;                 // V' fragment order (adjacent:
                                                  //  one-past K prefetch lands here)
    __hip_bfloat16* a2 = xb;                      // alias: xb dead after qkv

    cvt_x<<<1024, 256, 0, stream>>>(x, xb);
    qkv_kernel<<<dim3(128, 15), 256, 0, stream>>>(xb, w_qkv, q, kp, vp);
    attn_kernel<<<dim3(64, 40), 128, 0, stream>>>(q, kp, vp, a2);
    proj_kernel<<<dim3(128, 5), 256, 0, stream>>>(a2, w_proj, b_proj, out);
}